// Round 16
// baseline (514.740 us; speedup 1.0000x reference)
//
#include <hip/hip_runtime.h>
#include <hip/hip_fp8.h>

typedef short bf16x8 __attribute__((ext_vector_type(8)));
typedef float f32x4 __attribute__((ext_vector_type(4)));
typedef unsigned short u16;
typedef unsigned char u8;

#define GLDS16(g, l) __builtin_amdgcn_global_load_lds( \
    (const __attribute__((address_space(1))) void*)(g), \
    (__attribute__((address_space(3))) void*)(l), 16, 0, 0)

// opaque-to-legalizer LDS reads
#define DSR_(dst, p) asm volatile("ds_read_b128 %0, %1" \
    : "=v"(dst) : "v"((const __attribute__((address_space(3))) void*)(p)))
#define DSR64_(dst, p) asm volatile("ds_read_b64 %0, %1" \
    : "=v"(dst) : "v"((const __attribute__((address_space(3))) void*)(p)))

__device__ __forceinline__ u16 f2b(float f) {
  unsigned u = __float_as_uint(f);
  u += 0x7fffu + ((u >> 16) & 1u);
  return (u16)(u >> 16);
}
__device__ __forceinline__ float b2f(u16 b) {
  return __uint_as_float(((unsigned)b) << 16);
}
__device__ __forceinline__ u8 f2e4(float v) {
  __hip_fp8_e4m3 t(v);
  return *reinterpret_cast<u8*>(&t);
}

// ---------------- plain weight transpose + bf16: w[K][N] -> wt[N][K] ----------------
__global__ __launch_bounds__(256)
void transpose_bf16(const float* __restrict__ w, u16* __restrict__ wt, int K, int N) {
  __shared__ float tile[32][33];
  const int n0 = blockIdx.x * 32, k0 = blockIdx.y * 32;
  const int tx = threadIdx.x & 31, ty = threadIdx.x >> 5;
#pragma unroll
  for (int i = 0; i < 4; ++i)
    tile[ty + i * 8][tx] = w[(size_t)(k0 + ty + i * 8) * N + n0 + tx];
  __syncthreads();
#pragma unroll
  for (int i = 0; i < 4; ++i)
    wt[(size_t)(n0 + ty + i * 8) * K + k0 + tx] = f2b(tile[tx][ty + i * 8]);
}

// ---------------- weight transpose + fp8 (x16 scale): w[K][N] -> wt8[N][K] ----------------
__global__ __launch_bounds__(256)
void transpose_fp8(const float* __restrict__ w, u8* __restrict__ wt, int K, int N) {
  __shared__ float tile[32][33];
  const int n0 = blockIdx.x * 32, k0 = blockIdx.y * 32;
  const int tx = threadIdx.x & 31, ty = threadIdx.x >> 5;
#pragma unroll
  for (int i = 0; i < 4; ++i)
    tile[ty + i * 8][tx] = w[(size_t)(k0 + ty + i * 8) * N + n0 + tx];
  __syncthreads();
#pragma unroll
  for (int i = 0; i < 4; ++i)
    wt[(size_t)(n0 + ty + i * 8) * K + k0 + tx] = f2e4(16.f * tile[tx][ty + i * 8]);
}

// ---------------- QKV transpose + parity pack: w[1024][3072] -> wp[2][1536][1024] ----------------
__global__ __launch_bounds__(256)
void transpose_qkv_pack(const float* __restrict__ w, u16* __restrict__ wp) {
  __shared__ float tile[32][33];
  const int n0 = blockIdx.x * 32, k0 = blockIdx.y * 32;
  const int tx = threadIdx.x & 31, ty = threadIdx.x >> 5;
#pragma unroll
  for (int i = 0; i < 4; ++i)
    tile[ty + i * 8][tx] = w[(size_t)(k0 + ty + i * 8) * 3072 + n0 + tx];
  __syncthreads();
#pragma unroll
  for (int i = 0; i < 4; ++i) {
    const int col = n0 + ty + i * 8;
    const int q = (col >> 6) & 1;
    const int np = (col >> 10) * 512 + ((col >> 7) & 7) * 64 + (col & 63);
    wp[(size_t)q * (1536 * 1024) + (size_t)np * 1024 + k0 + tx] = f2b(tile[tx][ty + i * 8]);
  }
}

// ---------------- W_O transpose + parity pack: w[1024][1024] -> wp[2][1024][512] ----------------
__global__ __launch_bounds__(256)
void transpose_wo_pack(const float* __restrict__ w, u16* __restrict__ wp) {
  __shared__ float tile[32][33];
  const int n0 = blockIdx.x * 32, k0 = blockIdx.y * 32;
  const int tx = threadIdx.x & 31, ty = threadIdx.x >> 5;
#pragma unroll
  for (int i = 0; i < 4; ++i)
    tile[ty + i * 8][tx] = w[(size_t)(k0 + ty + i * 8) * 1024 + n0 + tx];
  __syncthreads();
#pragma unroll
  for (int i = 0; i < 4; ++i) {
    const int n = n0 + ty + i * 8;
    const int k = k0 + tx;
    const int q = (k >> 6) & 1;
    const int kp = (k >> 7) * 64 + (k & 63);
    wp[(size_t)q * (1024 * 512) + (size_t)n * 512 + kp] = f2b(tile[tx][ty + i * 8]);
  }
}

// ---------------- layernorm -> bf16 or fp8(x4) row ----------------
template <int BF16IN, int OUT8>
__global__ __launch_bounds__(256)
void ln_rows(const void* __restrict__ srcv, const float* __restrict__ gam,
             const float* __restrict__ bet, const int* __restrict__ perm,
             void* __restrict__ dstv) {
  const int orow = blockIdx.x;
  const int b = orow >> 12, j = orow & 4095;
  const int srow = perm ? ((b << 12) + perm[j]) : orow;
  float4 v;
  if (BF16IN) {
    const uint2 raw = ((const uint2*)((const u16*)srcv + (size_t)srow * 1024))[threadIdx.x];
    v.x = b2f((u16)(raw.x & 0xffff)); v.y = b2f((u16)(raw.x >> 16));
    v.z = b2f((u16)(raw.y & 0xffff)); v.w = b2f((u16)(raw.y >> 16));
  } else {
    v = ((const float4*)((const float*)srcv + (size_t)srow * 1024))[threadIdx.x];
  }
  float s = v.x + v.y + v.z + v.w;
  float s2 = v.x * v.x + v.y * v.y + v.z * v.z + v.w * v.w;
#pragma unroll
  for (int d = 1; d < 64; d <<= 1) { s += __shfl_xor(s, d); s2 += __shfl_xor(s2, d); }
  __shared__ float rs[4], rs2[4];
  const int wave = threadIdx.x >> 6, lane = threadIdx.x & 63;
  if (lane == 0) { rs[wave] = s; rs2[wave] = s2; }
  __syncthreads();
  s = rs[0] + rs[1] + rs[2] + rs[3];
  s2 = rs2[0] + rs2[1] + rs2[2] + rs2[3];
  const float mu = s * (1.f / 1024.f);
  const float var = s2 * (1.f / 1024.f) - mu * mu;
  const float rstd = rsqrtf(var + 1e-5f);
  const int c = threadIdx.x * 4;
  const float4 gg = *(const float4*)(gam + c);
  const float4 bb = *(const float4*)(bet + c);
  const float o0 = (v.x - mu) * rstd * gg.x + bb.x;
  const float o1 = (v.y - mu) * rstd * gg.y + bb.y;
  const float o2 = (v.z - mu) * rstd * gg.z + bb.z;
  const float o3 = (v.w - mu) * rstd * gg.w + bb.w;
  if (OUT8) {
    const unsigned p = (unsigned)f2e4(4.f * o0) | ((unsigned)f2e4(4.f * o1) << 8) |
                       ((unsigned)f2e4(4.f * o2) << 16) | ((unsigned)f2e4(4.f * o3) << 24);
    *(unsigned*)((u8*)dstv + (size_t)orow * 1024 + c) = p;
  } else {
    const unsigned lo = (unsigned)f2b(o0) | ((unsigned)f2b(o1) << 16);
    const unsigned hi = (unsigned)f2b(o2) | ((unsigned)f2b(o3) << 16);
    *(uint2*)((u16*)dstv + (size_t)orow * 1024 + c) = make_uint2(lo, hi);
  }
}

// ---------------- 256x256 bf16 GEMM (R10 pipeline) — QKV / O-proj ----------------
template <int EPI, int PAR>
__global__ __launch_bounds__(512, 2)
void gemm256(const u16* __restrict__ A, const u16* __restrict__ Bt,
             const float* __restrict__ bias, void* __restrict__ Cout,
             const void* __restrict__ resid, const int* __restrict__ perm,
             int M, int Nn, int K, int aRS,
             long aParOff, long bParOff, long cParOff) {
  __shared__ u16 sm[65536];
  char* const smc = (char*)sm;
  const int tid = threadIdx.x;
  const int w = tid >> 6, lane = tid & 63;
  const int lr = lane & 15, lg = lane >> 4;
  const int wm = w >> 2, wn = w & 3;

  int wg = blockIdx.x;
  int par = 0;
  if (PAR) { par = wg & 1; wg >>= 1; }
  const int x = wg & 7, l = wg >> 3;
  const int band = (M >> 8) >> 3;
  const int mm = l % band, nn = l / band;
  const int m0 = (x * band + mm) << 8;
  const int n0 = nn << 8;

  const int srow = tid >> 3;
  const int scol = ((tid & 7) ^ (srow & 7)) << 3;
  const size_t aSrc = (size_t)(m0 + srow) * aRS + (PAR ? (size_t)par * aParOff : 0) + scol;
  const size_t bSrc = (size_t)(n0 + srow) * K + (PAR ? (size_t)par * bParOff : 0) + scol;

  const int slot0 = (lg ^ (lr & 7)) << 4;
  const int aRow = (wm * 128 + lr) * 128;
  const int bRow = 32768 + (wn * 64 + lr) * 128;

  const int NT = K >> 6;

#define STAGE_(d, mat, h, k0) do { \
    const size_t rs_ = (mat) ? (size_t)K : (size_t)aRS; \
    const u16* gp = ((mat) ? Bt : A) + ((mat) ? bSrc : aSrc) + (size_t)(h) * 128 * rs_ + (k0); \
    char* lp = smc + (d) * 65536 + (mat) * 32768 + (h) * 16384 + w * 1024; \
    GLDS16(gp, lp); GLDS16(gp + 64 * rs_, lp + 8192); } while (0)

  bf16x8 aLo[8], aHi[8], bLo[4], bHi[4];

#define R_ALO(P) do { _Pragma("unroll") for (int mf = 0; mf < 4; ++mf) \
    _Pragma("unroll") for (int kk = 0; kk < 2; ++kk) \
      DSR_(aLo[mf * 2 + kk], (P) + aRow + mf * 2048 + (slot0 ^ (kk << 6))); } while (0)
#define R_AHI(P) do { _Pragma("unroll") for (int mf = 0; mf < 4; ++mf) \
    _Pragma("unroll") for (int kk = 0; kk < 2; ++kk) \
      DSR_(aHi[mf * 2 + kk], (P) + aRow + (4 + mf) * 2048 + (slot0 ^ (kk << 6))); } while (0)
#define R_BLO(P) do { _Pragma("unroll") for (int nf = 0; nf < 2; ++nf) \
    _Pragma("unroll") for (int kk = 0; kk < 2; ++kk) \
      DSR_(bLo[nf * 2 + kk], (P) + bRow + nf * 2048 + (slot0 ^ (kk << 6))); } while (0)
#define R_BHI(P) do { _Pragma("unroll") for (int nf = 0; nf < 2; ++nf) \
    _Pragma("unroll") for (int kk = 0; kk < 2; ++kk) \
      DSR_(bHi[nf * 2 + kk], (P) + bRow + (2 + nf) * 2048 + (slot0 ^ (kk << 6))); } while (0)

#define QUAD_(AARR, BARR, MB, NB) do { _Pragma("unroll") for (int mf = 0; mf < 4; ++mf) \
    _Pragma("unroll") for (int nf = 0; nf < 2; ++nf) \
    _Pragma("unroll") for (int kk = 0; kk < 2; ++kk) \
      acc[(MB) * 4 + mf][(NB) * 2 + nf] = __builtin_amdgcn_mfma_f32_16x16x32_bf16( \
          AARR[mf * 2 + kk], BARR[nf * 2 + kk], acc[(MB) * 4 + mf][(NB) * 2 + nf], 0, 0, 0); } while (0)

#define LGKM0SB_() do { asm volatile("s_waitcnt lgkmcnt(0)" ::: "memory"); \
                        __builtin_amdgcn_sched_barrier(0); } while (0)

  STAGE_(0, 1, 0, 0); STAGE_(0, 1, 1, 0); STAGE_(0, 0, 0, 0); STAGE_(0, 0, 1, 0);
  if (NT > 1) {
    STAGE_(1, 1, 0, 64); STAGE_(1, 1, 1, 64); STAGE_(1, 0, 0, 64); STAGE_(1, 0, 1, 64);
    asm volatile("s_waitcnt vmcnt(8)" ::: "memory");
  } else {
    asm volatile("s_waitcnt vmcnt(0)" ::: "memory");
  }
  __builtin_amdgcn_s_barrier();

  f32x4 acc[8][4] = {};

  for (int t = 0; t < NT; ++t) {
    const int c = t & 1;
    const char* cbuf = smc + c * 65536;
    const int k2 = (t + 2) << 6;

    R_ALO(cbuf); R_BLO(cbuf);
    LGKM0SB_();
    __builtin_amdgcn_s_setprio(1);
    QUAD_(aLo, bLo, 0, 0);
    __builtin_amdgcn_s_setprio(0);
    R_BHI(cbuf);
    LGKM0SB_();
    __builtin_amdgcn_s_setprio(1);
    QUAD_(aLo, bHi, 0, 1);
    __builtin_amdgcn_s_setprio(0);
    __builtin_amdgcn_s_barrier();
    if (t + 2 < NT) { STAGE_(c, 1, 0, k2); STAGE_(c, 1, 1, k2); }
    R_AHI(cbuf);
    LGKM0SB_();
    __builtin_amdgcn_s_setprio(1);
    QUAD_(aHi, bLo, 1, 0);
    __builtin_amdgcn_s_setprio(0);
    __builtin_amdgcn_s_barrier();
    if (t + 2 < NT) { STAGE_(c, 0, 0, k2); STAGE_(c, 0, 1, k2); }
    __builtin_amdgcn_s_setprio(1);
    QUAD_(aHi, bHi, 1, 1);
    __builtin_amdgcn_s_setprio(0);
    if (t + 2 < NT) asm volatile("s_waitcnt vmcnt(8)" ::: "memory");
    else            asm volatile("s_waitcnt vmcnt(0)" ::: "memory");
    __builtin_amdgcn_s_barrier();
  }
#undef STAGE_
#undef R_ALO
#undef R_AHI
#undef R_BLO
#undef R_BHI
#undef QUAD_
#undef LGKM0SB_

#pragma unroll
  for (int mf = 0; mf < 8; ++mf) {
#pragma unroll
    for (int nf = 0; nf < 4; ++nf) {
      const int col = n0 + wn * 64 + nf * 16 + lr;
      float bia;
      if (PAR && EPI == 0) {
        const int s = col >> 9, hh2 = (col >> 6) & 7, d = col & 63;
        bia = bias[s * 1024 + hh2 * 128 + par * 64 + d];
      } else {
        bia = bias[col];
      }
#pragma unroll
      for (int r = 0; r < 4; ++r) {
        const int row = m0 + wm * 128 + mf * 16 + lg * 4 + r;
        float v = acc[mf][nf][r] + bia;
        if (EPI == 0) {
          ((u16*)Cout)[(PAR ? (size_t)par * cParOff : 0) + (size_t)row * Nn + col] = f2b(v);
        } else if (EPI == 2) {
          const int orig = PAR ? (2 * row + par) : row;
          const int b2 = orig >> 12, jj = orig & 4095;
          const size_t di = ((size_t)((b2 << 12) + perm[jj])) * 1024 + col;
          ((u16*)Cout)[di] = f2b(((const float*)resid)[di] + v);   // x2(bf16) = x + oproj
        } else {
          const size_t di = (size_t)row * 1024 + col;
          ((float*)Cout)[di] = b2f(((const u16*)resid)[di]) + v;   // out = x2(bf16) + mlp
        }
      }
    }
  }
}

// ---------------- 256x128 bf16 GEMM, BK=32, 48 KiB LDS, 2 blocks/CU — MLP2 ----------------
// out_f32 = resid_bf16 + A@Bt + bias. Grid 512 (2/CU resident) so one block's MFMA
// overlaps the other's barrier/vmcnt stalls. Swizzle: 64-B rows, slot = lg ^ ((r>>1)&3)
// (verified 2-way/bank = free); DMA source pre-swizzled with the same lane-only term.
__global__ __launch_bounds__(512, 4)
void gemm_bk32(const u16* __restrict__ A, const u16* __restrict__ Bt,
               const float* __restrict__ bias, float* __restrict__ Cout,
               const u16* __restrict__ resid, int M, int Nn, int K) {
  __shared__ u16 sm[24576];                 // 2 bufs x {A 16K, B 8K}
  char* const smc = (char*)sm;
  const int tid = threadIdx.x;
  const int w = tid >> 6, lane = tid & 63;
  const int lr = lane & 15, lg = lane >> 4;
  const int wm = w >> 2, wn = w & 3;

  const int wg = blockIdx.x;
  const int x = wg & 7, l = wg >> 3;         // band = 8 m-tiles per XCD
  const int mm = l & 7, nn = l >> 3;         // nn 0..7 (Nn=1024, BN=128)
  const int m0 = ((x << 3) + mm) << 8;
  const int n0 = nn << 7;

  // staging lane constants
  const int sr = lane >> 2, sj = lane & 3;
  const int sc = ((sj ^ ((sr >> 1) & 3)) << 3);          // global elem col
  // read-side swizzled slot (lane-only: ((r>>1)&3) == ((lr>>1)&3))
  const int sw = (lg ^ ((lr >> 1) & 3)) << 4;
  const int aRowB = (wm * 128 + lr) * 64;
  const int bRowB = 16384 + (wn * 32 + lr) * 64;

  const int NT = K >> 5;

  // A: wave w stages rows [w*32, w*32+32): 2 glds; B: rows [w*16, w*16+16): 1 glds
#define STAGEA_(d, i, k0) do { \
    const int rr = w * 32 + (i) * 16 + sr; \
    GLDS16(A + (size_t)(m0 + rr) * K + (k0) + sc, \
           smc + (d) * 24576 + w * 2048 + (i) * 1024); } while (0)
#define STAGEB_(d, k0) do { \
    const int rr = w * 16 + sr; \
    GLDS16(Bt + (size_t)(n0 + rr) * K + (k0) + sc, \
           smc + (d) * 24576 + 16384 + w * 1024); } while (0)
#define STAGET_(d, k0) do { STAGEA_(d, 0, k0); STAGEA_(d, 1, k0); STAGEB_(d, k0); } while (0)

  bf16x8 a[8], b[2];

#define R_T(P) do { _Pragma("unroll") for (int mf = 0; mf < 8; ++mf) \
      DSR_(a[mf], (P) + aRowB + mf * 1024 + sw); \
    _Pragma("unroll") for (int nf = 0; nf < 2; ++nf) \
      DSR_(b[nf], (P) + bRowB + nf * 1024 + sw); } while (0)

#define LGKM0SB_() do { asm volatile("s_waitcnt lgkmcnt(0)" ::: "memory"); \
                        __builtin_amdgcn_sched_barrier(0); } while (0)

  // prologue: t0 -> buf0, t1 -> buf1; wait t0 (leave t1's 3 in flight)
  STAGET_(0, 0);
  if (NT > 1) { STAGET_(1, 32); asm volatile("s_waitcnt vmcnt(3)" ::: "memory"); }
  else        { asm volatile("s_waitcnt vmcnt(0)" ::: "memory"); }
  __builtin_amdgcn_s_barrier();

  f32x4 acc[8][2] = {};

  for (int t = 0; t < NT; ++t) {
    const int c = t & 1;
    R_T(smc + c * 24576);
    LGKM0SB_();
    __builtin_amdgcn_s_setprio(1);
#pragma unroll
    for (int mf = 0; mf < 8; ++mf)
#pragma unroll
      for (int nf = 0; nf < 2; ++nf)
        acc[mf][nf] = __builtin_amdgcn_mfma_f32_16x16x32_bf16(a[mf], b[nf], acc[mf][nf], 0, 0, 0);
    __builtin_amdgcn_s_setprio(0);
    __builtin_amdgcn_s_barrier();            // all waves done reading buf c
    if (t + 2 < NT) STAGET_(c, (t + 2) << 5);
    if (t + 2 < NT) asm volatile("s_waitcnt vmcnt(3)" ::: "memory");
    else            asm volatile("s_waitcnt vmcnt(0)" ::: "memory");
    __builtin_amdgcn_s_barrier();            // tile t+1 published
  }
#undef STAGEA_
#undef STAGEB_
#undef STAGET_
#undef R_T
#undef LGKM0SB_

#pragma unroll
  for (int mf = 0; mf < 8; ++mf) {
#pragma unroll
    for (int nf = 0; nf < 2; ++nf) {
      const int col = n0 + wn * 32 + nf * 16 + lr;
      const float bia = bias[col];
#pragma unroll
      for (int r = 0; r < 4; ++r) {
        const int row = m0 + wm * 128 + mf * 16 + lg * 4 + r;
        const size_t di = (size_t)row * 1024 + col;
        Cout[di] = b2f(resid[di]) + acc[mf][nf][r] + bia;
      }
    }
  }
}

// ---------------- 256x256 fp8 GEMM, BK=128 — MLP1 only ----------------
// A pre-scaled x4 (fp8), B pre-scaled x16 (fp8) -> acc descaled 1/64; GELU -> bf16 store.
__global__ __launch_bounds__(512, 2)
void gemm_f8(const u8* __restrict__ A, const u8* __restrict__ Bt,
             const float* __restrict__ bias, u16* __restrict__ Cout,
             int M, int Nn, int K) {
  __shared__ u16 sm[65536];                 // 2 bufs x {A 32K, B 32K} (fp8, BK=128)
  char* const smc = (char*)sm;
  const int tid = threadIdx.x;
  const int w = tid >> 6, lane = tid & 63;
  const int lr = lane & 15, lg = lane >> 4;
  const int wm = w >> 2, wn = w & 3;

  const int wg = blockIdx.x;
  const int x = wg & 7, l = wg >> 3;
  const int band = (M >> 8) >> 3;
  const int mm = l % band, nn = l / band;
  const int m0 = (x * band + mm) << 8;
  const int n0 = nn << 8;

  const int srow8 = tid >> 3;
  const int scol8 = ((tid & 7) ^ ((srow8 >> 1) & 7)) << 4;
  const size_t aSrc = (size_t)(m0 + srow8) * K + scol8;
  const size_t bSrc = (size_t)(n0 + srow8) * K + scol8;

  const int aRowB = (wm * 128 + lr) * 128;
  const int bRowB = 32768 + (wn * 64 + lr) * 128;
  int slotf[4];
#pragma unroll
  for (int kk = 0; kk < 4; ++kk) slotf[kk] = ((kk * 4 + lg) ^ (lr & 14)) << 3;

  const int NT = K >> 7;

#define STAGE8_(d, mat, h, k0) do { \
    const u8* gp = ((mat) ? Bt : A) + ((mat) ? bSrc : aSrc) + (size_t)(h) * 128 * K + (k0); \
    char* lp = smc + (d) * 65536 + (mat) * 32768 + (h) * 16384 + w * 1024; \
    GLDS16(gp, lp); GLDS16(gp + (size_t)64 * K, lp + 8192); } while (0)

  long aLo[16], aHi[16], bLo[8], bHi[8];

#define R8_ALO(P) do { _Pragma("unroll") for (int mf = 0; mf < 4; ++mf) \
    _Pragma("unroll") for (int kk = 0; kk < 4; ++kk) \
      DSR64_(aLo[mf * 4 + kk], (P) + aRowB + mf * 2048 + slotf[kk]); } while (0)
#define R8_AHI(P) do { _Pragma("unroll") for (int mf = 0; mf < 4; ++mf) \
    _Pragma("unroll") for (int kk = 0; kk < 4; ++kk) \
      DSR64_(aHi[mf * 4 + kk], (P) + aRowB + (4 + mf) * 2048 + slotf[kk]); } while (0)
#define R8_BLO(P) do { _Pragma("unroll") for (int nf = 0; nf < 2; ++nf) \
    _Pragma("unroll") for (int kk = 0; kk < 4; ++kk) \
      DSR64_(bLo[nf * 4 + kk], (P) + bRowB + nf * 2048 + slotf[kk]); } while (0)
#define R8_BHI(P) do { _Pragma("unroll") for (int nf = 0; nf < 2; ++nf) \
    _Pragma("unroll") for (int kk = 0; kk < 4; ++kk) \
      DSR64_(bHi[nf * 4 + kk], (P) + bRowB + (2 + nf) * 2048 + slotf[kk]); } while (0)

#define QUAD8_(AARR, BARR, MB, NB) do { _Pragma("unroll") for (int kk = 0; kk < 4; ++kk) \
    _Pragma("unroll") for (int mf = 0; mf < 4; ++mf) \
    _Pragma("unroll") for (int nf = 0; nf < 2; ++nf) \
      acc[(MB) * 4 + mf][(NB) * 2 + nf] = __builtin_amdgcn_mfma_f32_16x16x32_fp8_fp8( \
          AARR[mf * 4 + kk], BARR[nf * 4 + kk], acc[(MB) * 4 + mf][(NB) * 2 + nf], 0, 0, 0); } while (0)

#define LGKM0SB_() do { asm volatile("s_waitcnt lgkmcnt(0)" ::: "memory"); \
                        __builtin_amdgcn_sched_barrier(0); } while (0)

  STAGE8_(0, 1, 0, 0); STAGE8_(0, 1, 1, 0); STAGE8_(0, 0, 0, 0); STAGE8_(0, 0, 1, 0);
  if (NT > 1) {
    STAGE8_(1, 1, 0, 128); STAGE8_(1, 1, 1, 128); STAGE8_(1, 0, 0, 128); STAGE8_(1, 0, 1, 128);
    asm volatile("s_waitcnt vmcnt(8)" ::: "memory");
  } else {
    asm volatile("s_waitcnt vmcnt(0)" ::: "memory");
  }
  __builtin_amdgcn_s_barrier();

  f32x4 acc[8][4] = {};

  for (int t = 0; t < NT; ++t) {
    const int c = t & 1;
    const char* cbuf = smc + c * 65536;
    const int k2 = (t + 2) << 7;

    R8_ALO(cbuf); R8_BLO(cbuf);
    LGKM0SB_();
    __builtin_amdgcn_s_setprio(1);
    QUAD8_(aLo, bLo, 0, 0);
    __builtin_amdgcn_s_setprio(0);
    R8_BHI(cbuf);
    LGKM0SB_();
    __builtin_amdgcn_s_setprio(1);
    QUAD8_(aLo, bHi, 0, 1);
    __builtin_amdgcn_s_setprio(0);
    __builtin_amdgcn_s_barrier();
    if (t + 2 < NT) { STAGE8_(c, 1, 0, k2); STAGE8_(c, 1, 1, k2); }
    R8_AHI(cbuf);
    LGKM0SB_();
    __builtin_amdgcn_s_setprio(1);
    QUAD8_(aHi, bLo, 1, 0);
    __builtin_amdgcn_s_setprio(0);
    __builtin_amdgcn_s_barrier();
    if (t + 2 < NT) { STAGE8_(c, 0, 0, k2); STAGE8_(c, 0, 1, k2); }
    __builtin_amdgcn_s_setprio(1);
    QUAD8_(aHi, bHi, 1, 1);
    __builtin_amdgcn_s_setprio(0);
    if (t + 2 < NT) asm volatile("s_waitcnt vmcnt(8)" ::: "memory");
    else            asm volatile("s_waitcnt vmcnt(0)" ::: "memory");
    __builtin_amdgcn_s_barrier();
  }
#undef STAGE8_
#undef R8_ALO
#undef R8_AHI
#undef R8_BLO
#undef R8_BHI
#undef QUAD8_
#undef LGKM0SB_

#pragma unroll
  for (int mf = 0; mf < 8; ++mf) {
#pragma unroll
    for (int nf = 0; nf < 4; ++nf) {
      const int col = n0 + wn * 64 + nf * 16 + lr;
      const float bia = bias[col];
#pragma unroll
      for (int r = 0; r < 4; ++r) {
        const int row = m0 + wm * 128 + mf * 16 + lg * 4 + r;
        float v = acc[mf][nf][r] * 0.015625f + bia;
        v = 0.5f * v * (1.f + erff(v * 0.70710678118654752f));
        Cout[(size_t)row * Nn + col] = f2b(v);
      }
    }
  }
}

// ---------------- dilated attention on parity-packed buffers ----------------
__global__ __launch_bounds__(256, 2)
void attn_kernel(const u16* __restrict__ qkvp, u16* __restrict__ op) {
  const int blk = blockIdx.x;
  const int h = blk & 15, g = (blk >> 4) & 15, b = blk >> 8;
  const int tid = threadIdx.x, wave = tid >> 6, lane = tid & 63;
  const int lr = lane & 15, lg = lane >> 4;
  const int par = h & 1, hh = h >> 1;

  __shared__ u16 lQ[128 * 64];
  __shared__ u16 lK[128 * 64];
  __shared__ u16 lVt[64 * 128];
  __shared__ u16 lP[4][32 * 128];

  const u16* qp = qkvp + (size_t)par * (8192 * 1536);
  u16* opb = op + (size_t)par * (8192 * 512);
  const int rbase = (b << 11) + (g << 7);

#pragma unroll
  for (int i = 0; i < 4; ++i) {
    const int ou = i * 4096 + wave * 1024;
    const int o = ou + lane * 16;
    const int j = o >> 7, cb = o & 127;
    const u16* gq = qp + (size_t)(rbase + j) * 1536 + hh * 64 + (cb >> 1);
    GLDS16(gq, (char*)lQ + ou);
    GLDS16(gq + 512, (char*)lK + ou);
  }
#pragma unroll
  for (int i = 0; i < 4; ++i) {
    const int c = tid + i * 256;
    const int j = c >> 3, dc = c & 7;
    const uint4 vv = *(const uint4*)(qp + (size_t)(rbase + j) * 1536 + 1024 + hh * 64 + dc * 8);
    const u16* pv = (const u16*)&vv;
#pragma unroll
    for (int e = 0; e < 8; ++e) lVt[(dc * 8 + e) * 128 + j] = pv[e];
  }
  __syncthreads();

  f32x4 sacc[2][8] = {};
#pragma unroll
  for (int kk = 0; kk < 2; ++kk) {
    bf16x8 aq[2], bk[8];
#pragma unroll
    for (int mf = 0; mf < 2; ++mf)
      aq[mf] = *(const bf16x8*)&lQ[(wave * 32 + mf * 16 + lr) * 64 + kk * 32 + lg * 8];
#pragma unroll
    for (int nf = 0; nf < 8; ++nf)
      bk[nf] = *(const bf16x8*)&lK[(nf * 16 + lr) * 64 + kk * 32 + lg * 8];
#pragma unroll
    for (int mf = 0; mf < 2; ++mf)
#pragma unroll
      for (int nf = 0; nf < 8; ++nf)
        sacc[mf][nf] = __builtin_amdgcn_mfma_f32_16x16x32_bf16(aq[mf], bk[nf], sacc[mf][nf], 0, 0, 0);
  }

#pragma unroll
  for (int mf = 0; mf < 2; ++mf) {
#pragma unroll
    for (int r = 0; r < 4; ++r) {
      float mx = -3e38f;
#pragma unroll
      for (int nf = 0; nf < 8; ++nf) mx = fmaxf(mx, sacc[mf][nf][r]);
#pragma unroll
      for (int d = 1; d < 16; d <<= 1) mx = fmaxf(mx, __shfl_xor(mx, d));
      float pv[8];
      float sum = 0.f;
#pragma unroll
      for (int nf = 0; nf < 8; ++nf) {
        pv[nf] = __expf((sacc[mf][nf][r] - mx) * 0.125f);
        sum += pv[nf];
      }
#pragma unroll
      for (int d = 1; d < 16; d <<= 1) sum += __shfl_xor(sum, d);
      const float inv = 1.f / sum;
      const int rrow = mf * 16 + lg * 4 + r;
#pragma unroll
      for (int nf = 0; nf < 8; ++nf)
        lP[wave][rrow * 128 + nf * 16 + lr] = f2b(pv[nf] * inv);
    }
  }
  __syncthreads();

  f32x4 oacc[2][4] = {};
#pragma unroll
  for (int kk = 0; kk < 4; ++kk) {
    bf16x8 ap[2], bv[4];
#pragma unroll
    for (int mf = 0; mf < 2; ++mf)
      ap[mf] = *(const bf16x8*)&lP[wave][(mf * 16 + lr) * 128 + kk * 32 + lg * 8];
#pragma unroll
    for (int nf = 0; nf < 4; ++nf)
      bv[nf] = *(const bf16x8*)&lVt[(nf * 16 + lr) * 128 + kk * 32 + lg * 8];
#pragma unroll
    for (int mf = 0; mf < 2; ++mf)
#pragma unroll
      for (int nf = 0; nf < 4; ++nf)
        oacc[mf][nf] = __builtin_amdgcn_mfma_f32_16x16x32_bf16(ap[mf], bv[nf], oacc[mf][nf], 0, 0, 0);
  }

  u16* obase = opb + (size_t)rbase * 512 + hh * 64;
#pragma unroll
  for (int mf = 0; mf < 2; ++mf)
#pragma unroll
    for (int nf = 0; nf < 4; ++nf)
#pragma unroll
      for (int r = 0; r < 4; ++r) {
        const int jq = wave * 32 + mf * 16 + lg * 4 + r;
        obase[(size_t)jq * 512 + nf * 16 + lr] = f2b(oacc[mf][nf][r]);
      }
}

// ---------------- launch ----------------
extern "C" void kernel_launch(void* const* d_in, const int* in_sizes, int n_in,
                              void* d_out, int out_size, void* d_ws, size_t ws_size,
                              hipStream_t stream) {
  const float* x    = (const float*)d_in[0];
  const float* ln1g = (const float*)d_in[1];
  const float* ln1b = (const float*)d_in[2];
  const float* wqkv = (const float*)d_in[3];
  const float* bqkv = (const float*)d_in[4];
  const float* wo   = (const float*)d_in[5];
  const float* bo   = (const float*)d_in[6];
  const float* ln2g = (const float*)d_in[7];
  const float* ln2b = (const float*)d_in[8];
  const float* w1   = (const float*)d_in[9];
  const float* b1   = (const float*)d_in[10];
  const float* w2   = (const float*)d_in[11];
  const float* b2   = (const float*)d_in[12];
  const int*   perm = (const int*)d_in[13];
  float* out = (float*)d_out;
  char* ws = (char*)d_ws;

  u16*  r0    = (u16*)ws;                         // 32 MB: LN1 out (bf16) / LN2 out (fp8)
  u8*   r8    = (u8*)ws;
  u16*  qkvp  = (u16*)(ws + (32ull << 20));       // 48 MB: [2][8192][1536]
  u16*  op    = (u16*)(ws + (80ull << 20));       // 16 MB: [2][8192][512]
  u16*  a1    = (u16*)(ws + (32ull << 20));       // 128 MB bf16 (qkvp/op dead by then)
  u16*  x2    = (u16*)(ws + (160ull << 20));      // 32 MB (bf16 residual)
  u16*  wqkvP = (u16*)(ws + (224ull << 20));      // 6 MB
  u16*  woP   = (u16*)(ws + (230ull << 20));      // 2 MB
  u8*   w1T8  = (u8*)(ws + (232ull << 20));       // 4 MB fp8
  u16*  w2T   = (u16*)(ws + (240ull << 20));      // 8 MB bf16

  transpose_qkv_pack<<<dim3(96, 32), 256, 0, stream>>>(wqkv, wqkvP);
  transpose_wo_pack<<<dim3(32, 32), 256, 0, stream>>>(wo, woP);
  transpose_fp8<<<dim3(4096 / 32, 1024 / 32), 256, 0, stream>>>(w1, w1T8, 1024, 4096);
  transpose_bf16<<<dim3(1024 / 32, 4096 / 32), 256, 0, stream>>>(w2, w2T, 4096, 1024);

  ln_rows<0, 0><<<16384, 256, 0, stream>>>(x, ln1g, ln1b, perm, r0);      // LN1(x)[perm] bf16
  gemm256<0, 1><<<384, 512, 0, stream>>>(r0, wqkvP, bqkv, qkvp, nullptr, nullptr,
                                         8192, 1536, 1024, 2048,
                                         1024L, 1536L * 1024, 8192L * 1536);
  attn_kernel<<<1024, 256, 0, stream>>>(qkvp, op);
  gemm256<2, 1><<<256, 512, 0, stream>>>(op, woP, bo, x2, x, perm,
                                         8192, 1024, 512, 512,
                                         8192L * 512, 1024L * 512, 0);
  ln_rows<1, 1><<<16384, 256, 0, stream>>>(x2, ln2g, ln2b, nullptr, r8);  // LN2 -> fp8 (x4)
  gemm_f8<<<1024, 512, 0, stream>>>(r8, w1T8, b1, a1, 16384, 4096, 1024); // a1 = gelu (bf16)
  gemm_bk32<<<512, 512, 0, stream>>>(a1, w2T, b2, out, x2,
                                     16384, 1024, 4096);                  // out = x2 + mlp2
}

// Round 17
// 489.680 us; speedup vs baseline: 1.0512x; 1.0512x over previous
//
#include <hip/hip_runtime.h>
#include <hip/hip_fp8.h>

typedef short bf16x8 __attribute__((ext_vector_type(8)));
typedef float f32x4 __attribute__((ext_vector_type(4)));
typedef unsigned short u16;
typedef unsigned char u8;

#define GLDS16(g, l) __builtin_amdgcn_global_load_lds( \
    (const __attribute__((address_space(1))) void*)(g), \
    (__attribute__((address_space(3))) void*)(l), 16, 0, 0)

// opaque-to-legalizer LDS reads
#define DSR_(dst, p) asm volatile("ds_read_b128 %0, %1" \
    : "=v"(dst) : "v"((const __attribute__((address_space(3))) void*)(p)))
#define DSR64_(dst, p) asm volatile("ds_read_b64 %0, %1" \
    : "=v"(dst) : "v"((const __attribute__((address_space(3))) void*)(p)))

__device__ __forceinline__ u16 f2b(float f) {
  unsigned u = __float_as_uint(f);
  u += 0x7fffu + ((u >> 16) & 1u);
  return (u16)(u >> 16);
}
__device__ __forceinline__ float b2f(u16 b) {
  return __uint_as_float(((unsigned)b) << 16);
}
__device__ __forceinline__ u8 f2e4(float v) {
  __hip_fp8_e4m3 t(v);
  return *reinterpret_cast<u8*>(&t);
}

// ---------------- plain weight transpose + bf16: w[K][N] -> wt[N][K] ----------------
__global__ __launch_bounds__(256)
void transpose_bf16(const float* __restrict__ w, u16* __restrict__ wt, int K, int N) {
  __shared__ float tile[32][33];
  const int n0 = blockIdx.x * 32, k0 = blockIdx.y * 32;
  const int tx = threadIdx.x & 31, ty = threadIdx.x >> 5;
#pragma unroll
  for (int i = 0; i < 4; ++i)
    tile[ty + i * 8][tx] = w[(size_t)(k0 + ty + i * 8) * N + n0 + tx];
  __syncthreads();
#pragma unroll
  for (int i = 0; i < 4; ++i)
    wt[(size_t)(n0 + ty + i * 8) * K + k0 + tx] = f2b(tile[tx][ty + i * 8]);
}

// ---------------- weight transpose + fp8 (x16 scale): w[K][N] -> wt8[N][K] ----------------
__global__ __launch_bounds__(256)
void transpose_fp8(const float* __restrict__ w, u8* __restrict__ wt, int K, int N) {
  __shared__ float tile[32][33];
  const int n0 = blockIdx.x * 32, k0 = blockIdx.y * 32;
  const int tx = threadIdx.x & 31, ty = threadIdx.x >> 5;
#pragma unroll
  for (int i = 0; i < 4; ++i)
    tile[ty + i * 8][tx] = w[(size_t)(k0 + ty + i * 8) * N + n0 + tx];
  __syncthreads();
#pragma unroll
  for (int i = 0; i < 4; ++i)
    wt[(size_t)(n0 + ty + i * 8) * K + k0 + tx] = f2e4(16.f * tile[tx][ty + i * 8]);
}

// ---------------- QKV transpose + parity pack: w[1024][3072] -> wp[2][1536][1024] ----------------
__global__ __launch_bounds__(256)
void transpose_qkv_pack(const float* __restrict__ w, u16* __restrict__ wp) {
  __shared__ float tile[32][33];
  const int n0 = blockIdx.x * 32, k0 = blockIdx.y * 32;
  const int tx = threadIdx.x & 31, ty = threadIdx.x >> 5;
#pragma unroll
  for (int i = 0; i < 4; ++i)
    tile[ty + i * 8][tx] = w[(size_t)(k0 + ty + i * 8) * 3072 + n0 + tx];
  __syncthreads();
#pragma unroll
  for (int i = 0; i < 4; ++i) {
    const int col = n0 + ty + i * 8;
    const int q = (col >> 6) & 1;
    const int np = (col >> 10) * 512 + ((col >> 7) & 7) * 64 + (col & 63);
    wp[(size_t)q * (1536 * 1024) + (size_t)np * 1024 + k0 + tx] = f2b(tile[tx][ty + i * 8]);
  }
}

// ---------------- W_O transpose + parity pack: w[1024][1024] -> wp[2][1024][512] ----------------
__global__ __launch_bounds__(256)
void transpose_wo_pack(const float* __restrict__ w, u16* __restrict__ wp) {
  __shared__ float tile[32][33];
  const int n0 = blockIdx.x * 32, k0 = blockIdx.y * 32;
  const int tx = threadIdx.x & 31, ty = threadIdx.x >> 5;
#pragma unroll
  for (int i = 0; i < 4; ++i)
    tile[ty + i * 8][tx] = w[(size_t)(k0 + ty + i * 8) * 1024 + n0 + tx];
  __syncthreads();
#pragma unroll
  for (int i = 0; i < 4; ++i) {
    const int n = n0 + ty + i * 8;
    const int k = k0 + tx;
    const int q = (k >> 6) & 1;
    const int kp = (k >> 7) * 64 + (k & 63);
    wp[(size_t)q * (1024 * 512) + (size_t)n * 512 + kp] = f2b(tile[tx][ty + i * 8]);
  }
}

// ---------------- layernorm -> bf16 or fp8(x4) row ----------------
template <int BF16IN, int OUT8>
__global__ __launch_bounds__(256)
void ln_rows(const void* __restrict__ srcv, const float* __restrict__ gam,
             const float* __restrict__ bet, const int* __restrict__ perm,
             void* __restrict__ dstv) {
  const int orow = blockIdx.x;
  const int b = orow >> 12, j = orow & 4095;
  const int srow = perm ? ((b << 12) + perm[j]) : orow;
  float4 v;
  if (BF16IN) {
    const uint2 raw = ((const uint2*)((const u16*)srcv + (size_t)srow * 1024))[threadIdx.x];
    v.x = b2f((u16)(raw.x & 0xffff)); v.y = b2f((u16)(raw.x >> 16));
    v.z = b2f((u16)(raw.y & 0xffff)); v.w = b2f((u16)(raw.y >> 16));
  } else {
    v = ((const float4*)((const float*)srcv + (size_t)srow * 1024))[threadIdx.x];
  }
  float s = v.x + v.y + v.z + v.w;
  float s2 = v.x * v.x + v.y * v.y + v.z * v.z + v.w * v.w;
#pragma unroll
  for (int d = 1; d < 64; d <<= 1) { s += __shfl_xor(s, d); s2 += __shfl_xor(s2, d); }
  __shared__ float rs[4], rs2[4];
  const int wave = threadIdx.x >> 6, lane = threadIdx.x & 63;
  if (lane == 0) { rs[wave] = s; rs2[wave] = s2; }
  __syncthreads();
  s = rs[0] + rs[1] + rs[2] + rs[3];
  s2 = rs2[0] + rs2[1] + rs2[2] + rs2[3];
  const float mu = s * (1.f / 1024.f);
  const float var = s2 * (1.f / 1024.f) - mu * mu;
  const float rstd = rsqrtf(var + 1e-5f);
  const int c = threadIdx.x * 4;
  const float4 gg = *(const float4*)(gam + c);
  const float4 bb = *(const float4*)(bet + c);
  const float o0 = (v.x - mu) * rstd * gg.x + bb.x;
  const float o1 = (v.y - mu) * rstd * gg.y + bb.y;
  const float o2 = (v.z - mu) * rstd * gg.z + bb.z;
  const float o3 = (v.w - mu) * rstd * gg.w + bb.w;
  if (OUT8) {
    const unsigned p = (unsigned)f2e4(4.f * o0) | ((unsigned)f2e4(4.f * o1) << 8) |
                       ((unsigned)f2e4(4.f * o2) << 16) | ((unsigned)f2e4(4.f * o3) << 24);
    *(unsigned*)((u8*)dstv + (size_t)orow * 1024 + c) = p;
  } else {
    const unsigned lo = (unsigned)f2b(o0) | ((unsigned)f2b(o1) << 16);
    const unsigned hi = (unsigned)f2b(o2) | ((unsigned)f2b(o3) << 16);
    *(uint2*)((u16*)dstv + (size_t)orow * 1024 + c) = make_uint2(lo, hi);
  }
}

// ---------------- 256x256 bf16 GEMM (R10 pipeline) — QKV / O-proj / MLP2 ----------------
// EPI 0: bf16 store; 2: perm-scatter, x2_bf16 = x_f32 + v; 3: out_f32 = x2_bf16 + v.
template <int EPI, int PAR>
__global__ __launch_bounds__(512, 2)
void gemm256(const u16* __restrict__ A, const u16* __restrict__ Bt,
             const float* __restrict__ bias, void* __restrict__ Cout,
             const void* __restrict__ resid, const int* __restrict__ perm,
             int M, int Nn, int K, int aRS,
             long aParOff, long bParOff, long cParOff) {
  __shared__ u16 sm[65536];
  char* const smc = (char*)sm;
  const int tid = threadIdx.x;
  const int w = tid >> 6, lane = tid & 63;
  const int lr = lane & 15, lg = lane >> 4;
  const int wm = w >> 2, wn = w & 3;

  int wg = blockIdx.x;
  int par = 0;
  if (PAR) { par = wg & 1; wg >>= 1; }
  const int x = wg & 7, l = wg >> 3;
  const int band = (M >> 8) >> 3;
  const int mm = l % band, nn = l / band;
  const int m0 = (x * band + mm) << 8;
  const int n0 = nn << 8;

  const int srow = tid >> 3;
  const int scol = ((tid & 7) ^ (srow & 7)) << 3;
  const size_t aSrc = (size_t)(m0 + srow) * aRS + (PAR ? (size_t)par * aParOff : 0) + scol;
  const size_t bSrc = (size_t)(n0 + srow) * K + (PAR ? (size_t)par * bParOff : 0) + scol;

  const int slot0 = (lg ^ (lr & 7)) << 4;
  const int aRow = (wm * 128 + lr) * 128;
  const int bRow = 32768 + (wn * 64 + lr) * 128;

  const int NT = K >> 6;

#define STAGE_(d, mat, h, k0) do { \
    const size_t rs_ = (mat) ? (size_t)K : (size_t)aRS; \
    const u16* gp = ((mat) ? Bt : A) + ((mat) ? bSrc : aSrc) + (size_t)(h) * 128 * rs_ + (k0); \
    char* lp = smc + (d) * 65536 + (mat) * 32768 + (h) * 16384 + w * 1024; \
    GLDS16(gp, lp); GLDS16(gp + 64 * rs_, lp + 8192); } while (0)

  bf16x8 aLo[8], aHi[8], bLo[4], bHi[4];

#define R_ALO(P) do { _Pragma("unroll") for (int mf = 0; mf < 4; ++mf) \
    _Pragma("unroll") for (int kk = 0; kk < 2; ++kk) \
      DSR_(aLo[mf * 2 + kk], (P) + aRow + mf * 2048 + (slot0 ^ (kk << 6))); } while (0)
#define R_AHI(P) do { _Pragma("unroll") for (int mf = 0; mf < 4; ++mf) \
    _Pragma("unroll") for (int kk = 0; kk < 2; ++kk) \
      DSR_(aHi[mf * 2 + kk], (P) + aRow + (4 + mf) * 2048 + (slot0 ^ (kk << 6))); } while (0)
#define R_BLO(P) do { _Pragma("unroll") for (int nf = 0; nf < 2; ++nf) \
    _Pragma("unroll") for (int kk = 0; kk < 2; ++kk) \
      DSR_(bLo[nf * 2 + kk], (P) + bRow + nf * 2048 + (slot0 ^ (kk << 6))); } while (0)
#define R_BHI(P) do { _Pragma("unroll") for (int nf = 0; nf < 2; ++nf) \
    _Pragma("unroll") for (int kk = 0; kk < 2; ++kk) \
      DSR_(bHi[nf * 2 + kk], (P) + bRow + (2 + nf) * 2048 + (slot0 ^ (kk << 6))); } while (0)

#define QUAD_(AARR, BARR, MB, NB) do { _Pragma("unroll") for (int mf = 0; mf < 4; ++mf) \
    _Pragma("unroll") for (int nf = 0; nf < 2; ++nf) \
    _Pragma("unroll") for (int kk = 0; kk < 2; ++kk) \
      acc[(MB) * 4 + mf][(NB) * 2 + nf] = __builtin_amdgcn_mfma_f32_16x16x32_bf16( \
          AARR[mf * 2 + kk], BARR[nf * 2 + kk], acc[(MB) * 4 + mf][(NB) * 2 + nf], 0, 0, 0); } while (0)

#define LGKM0SB_() do { asm volatile("s_waitcnt lgkmcnt(0)" ::: "memory"); \
                        __builtin_amdgcn_sched_barrier(0); } while (0)

  STAGE_(0, 1, 0, 0); STAGE_(0, 1, 1, 0); STAGE_(0, 0, 0, 0); STAGE_(0, 0, 1, 0);
  if (NT > 1) {
    STAGE_(1, 1, 0, 64); STAGE_(1, 1, 1, 64); STAGE_(1, 0, 0, 64); STAGE_(1, 0, 1, 64);
    asm volatile("s_waitcnt vmcnt(8)" ::: "memory");
  } else {
    asm volatile("s_waitcnt vmcnt(0)" ::: "memory");
  }
  __builtin_amdgcn_s_barrier();

  f32x4 acc[8][4] = {};

  for (int t = 0; t < NT; ++t) {
    const int c = t & 1;
    const char* cbuf = smc + c * 65536;
    const int k2 = (t + 2) << 6;

    R_ALO(cbuf); R_BLO(cbuf);
    LGKM0SB_();
    __builtin_amdgcn_s_setprio(1);
    QUAD_(aLo, bLo, 0, 0);
    __builtin_amdgcn_s_setprio(0);
    R_BHI(cbuf);
    LGKM0SB_();
    __builtin_amdgcn_s_setprio(1);
    QUAD_(aLo, bHi, 0, 1);
    __builtin_amdgcn_s_setprio(0);
    __builtin_amdgcn_s_barrier();
    if (t + 2 < NT) { STAGE_(c, 1, 0, k2); STAGE_(c, 1, 1, k2); }
    R_AHI(cbuf);
    LGKM0SB_();
    __builtin_amdgcn_s_setprio(1);
    QUAD_(aHi, bLo, 1, 0);
    __builtin_amdgcn_s_setprio(0);
    __builtin_amdgcn_s_barrier();
    if (t + 2 < NT) { STAGE_(c, 0, 0, k2); STAGE_(c, 0, 1, k2); }
    __builtin_amdgcn_s_setprio(1);
    QUAD_(aHi, bHi, 1, 1);
    __builtin_amdgcn_s_setprio(0);
    if (t + 2 < NT) asm volatile("s_waitcnt vmcnt(8)" ::: "memory");
    else            asm volatile("s_waitcnt vmcnt(0)" ::: "memory");
    __builtin_amdgcn_s_barrier();
  }
#undef STAGE_
#undef R_ALO
#undef R_AHI
#undef R_BLO
#undef R_BHI
#undef QUAD_
#undef LGKM0SB_

#pragma unroll
  for (int mf = 0; mf < 8; ++mf) {
#pragma unroll
    for (int nf = 0; nf < 4; ++nf) {
      const int col = n0 + wn * 64 + nf * 16 + lr;
      float bia;
      if (PAR && EPI == 0) {
        const int s = col >> 9, hh2 = (col >> 6) & 7, d = col & 63;
        bia = bias[s * 1024 + hh2 * 128 + par * 64 + d];
      } else {
        bia = bias[col];
      }
#pragma unroll
      for (int r = 0; r < 4; ++r) {
        const int row = m0 + wm * 128 + mf * 16 + lg * 4 + r;
        float v = acc[mf][nf][r] + bia;
        if (EPI == 0) {
          ((u16*)Cout)[(PAR ? (size_t)par * cParOff : 0) + (size_t)row * Nn + col] = f2b(v);
        } else if (EPI == 2) {
          const int orig = PAR ? (2 * row + par) : row;
          const int b2 = orig >> 12, jj = orig & 4095;
          const size_t di = ((size_t)((b2 << 12) + perm[jj])) * 1024 + col;
          ((u16*)Cout)[di] = f2b(((const float*)resid)[di] + v);   // x2(bf16) = x + oproj
        } else {
          const size_t di = (size_t)row * 1024 + col;
          ((float*)Cout)[di] = b2f(((const u16*)resid)[di]) + v;   // out = x2(bf16) + mlp
        }
      }
    }
  }
}

// ---------------- 256x256 fp8 GEMM, BK=128 — MLP1 only ----------------
// A pre-scaled x4 (fp8), B pre-scaled x16 (fp8) -> acc descaled 1/64; GELU -> bf16 store.
__global__ __launch_bounds__(512, 2)
void gemm_f8(const u8* __restrict__ A, const u8* __restrict__ Bt,
             const float* __restrict__ bias, u16* __restrict__ Cout,
             int M, int Nn, int K) {
  __shared__ u16 sm[65536];                 // 2 bufs x {A 32K, B 32K} (fp8, BK=128)
  char* const smc = (char*)sm;
  const int tid = threadIdx.x;
  const int w = tid >> 6, lane = tid & 63;
  const int lr = lane & 15, lg = lane >> 4;
  const int wm = w >> 2, wn = w & 3;

  const int wg = blockIdx.x;
  const int x = wg & 7, l = wg >> 3;
  const int band = (M >> 8) >> 3;
  const int mm = l % band, nn = l / band;
  const int m0 = (x * band + mm) << 8;
  const int n0 = nn << 8;

  const int srow8 = tid >> 3;
  const int scol8 = ((tid & 7) ^ ((srow8 >> 1) & 7)) << 4;
  const size_t aSrc = (size_t)(m0 + srow8) * K + scol8;
  const size_t bSrc = (size_t)(n0 + srow8) * K + scol8;

  const int aRowB = (wm * 128 + lr) * 128;
  const int bRowB = 32768 + (wn * 64 + lr) * 128;
  int slotf[4];
#pragma unroll
  for (int kk = 0; kk < 4; ++kk) slotf[kk] = ((kk * 4 + lg) ^ (lr & 14)) << 3;

  const int NT = K >> 7;

#define STAGE8_(d, mat, h, k0) do { \
    const u8* gp = ((mat) ? Bt : A) + ((mat) ? bSrc : aSrc) + (size_t)(h) * 128 * K + (k0); \
    char* lp = smc + (d) * 65536 + (mat) * 32768 + (h) * 16384 + w * 1024; \
    GLDS16(gp, lp); GLDS16(gp + (size_t)64 * K, lp + 8192); } while (0)

  long aLo[16], aHi[16], bLo[8], bHi[8];

#define R8_ALO(P) do { _Pragma("unroll") for (int mf = 0; mf < 4; ++mf) \
    _Pragma("unroll") for (int kk = 0; kk < 4; ++kk) \
      DSR64_(aLo[mf * 4 + kk], (P) + aRowB + mf * 2048 + slotf[kk]); } while (0)
#define R8_AHI(P) do { _Pragma("unroll") for (int mf = 0; mf < 4; ++mf) \
    _Pragma("unroll") for (int kk = 0; kk < 4; ++kk) \
      DSR64_(aHi[mf * 4 + kk], (P) + aRowB + (4 + mf) * 2048 + slotf[kk]); } while (0)
#define R8_BLO(P) do { _Pragma("unroll") for (int nf = 0; nf < 2; ++nf) \
    _Pragma("unroll") for (int kk = 0; kk < 4; ++kk) \
      DSR64_(bLo[nf * 4 + kk], (P) + bRowB + nf * 2048 + slotf[kk]); } while (0)
#define R8_BHI(P) do { _Pragma("unroll") for (int nf = 0; nf < 2; ++nf) \
    _Pragma("unroll") for (int kk = 0; kk < 4; ++kk) \
      DSR64_(bHi[nf * 4 + kk], (P) + bRowB + (2 + nf) * 2048 + slotf[kk]); } while (0)

#define QUAD8_(AARR, BARR, MB, NB) do { _Pragma("unroll") for (int kk = 0; kk < 4; ++kk) \
    _Pragma("unroll") for (int mf = 0; mf < 4; ++mf) \
    _Pragma("unroll") for (int nf = 0; nf < 2; ++nf) \
      acc[(MB) * 4 + mf][(NB) * 2 + nf] = __builtin_amdgcn_mfma_f32_16x16x32_fp8_fp8( \
          AARR[mf * 4 + kk], BARR[nf * 4 + kk], acc[(MB) * 4 + mf][(NB) * 2 + nf], 0, 0, 0); } while (0)

#define LGKM0SB_() do { asm volatile("s_waitcnt lgkmcnt(0)" ::: "memory"); \
                        __builtin_amdgcn_sched_barrier(0); } while (0)

  STAGE8_(0, 1, 0, 0); STAGE8_(0, 1, 1, 0); STAGE8_(0, 0, 0, 0); STAGE8_(0, 0, 1, 0);
  if (NT > 1) {
    STAGE8_(1, 1, 0, 128); STAGE8_(1, 1, 1, 128); STAGE8_(1, 0, 0, 128); STAGE8_(1, 0, 1, 128);
    asm volatile("s_waitcnt vmcnt(8)" ::: "memory");
  } else {
    asm volatile("s_waitcnt vmcnt(0)" ::: "memory");
  }
  __builtin_amdgcn_s_barrier();

  f32x4 acc[8][4] = {};

  for (int t = 0; t < NT; ++t) {
    const int c = t & 1;
    const char* cbuf = smc + c * 65536;
    const int k2 = (t + 2) << 7;

    R8_ALO(cbuf); R8_BLO(cbuf);
    LGKM0SB_();
    __builtin_amdgcn_s_setprio(1);
    QUAD8_(aLo, bLo, 0, 0);
    __builtin_amdgcn_s_setprio(0);
    R8_BHI(cbuf);
    LGKM0SB_();
    __builtin_amdgcn_s_setprio(1);
    QUAD8_(aLo, bHi, 0, 1);
    __builtin_amdgcn_s_setprio(0);
    __builtin_amdgcn_s_barrier();
    if (t + 2 < NT) { STAGE8_(c, 1, 0, k2); STAGE8_(c, 1, 1, k2); }
    R8_AHI(cbuf);
    LGKM0SB_();
    __builtin_amdgcn_s_setprio(1);
    QUAD8_(aHi, bLo, 1, 0);
    __builtin_amdgcn_s_setprio(0);
    __builtin_amdgcn_s_barrier();
    if (t + 2 < NT) { STAGE8_(c, 0, 0, k2); STAGE8_(c, 0, 1, k2); }
    __builtin_amdgcn_s_setprio(1);
    QUAD8_(aHi, bHi, 1, 1);
    __builtin_amdgcn_s_setprio(0);
    if (t + 2 < NT) asm volatile("s_waitcnt vmcnt(8)" ::: "memory");
    else            asm volatile("s_waitcnt vmcnt(0)" ::: "memory");
    __builtin_amdgcn_s_barrier();
  }
#undef STAGE8_
#undef R8_ALO
#undef R8_AHI
#undef R8_BLO
#undef R8_BHI
#undef QUAD8_
#undef LGKM0SB_

#pragma unroll
  for (int mf = 0; mf < 8; ++mf) {
#pragma unroll
    for (int nf = 0; nf < 4; ++nf) {
      const int col = n0 + wn * 64 + nf * 16 + lr;
      const float bia = bias[col];
#pragma unroll
      for (int r = 0; r < 4; ++r) {
        const int row = m0 + wm * 128 + mf * 16 + lg * 4 + r;
        float v = acc[mf][nf][r] * 0.015625f + bia;
        v = 0.5f * v * (1.f + erff(v * 0.70710678118654752f));
        Cout[(size_t)row * Nn + col] = f2b(v);
      }
    }
  }
}

// ---------------- dilated attention on parity-packed buffers ----------------
__global__ __launch_bounds__(256, 2)
void attn_kernel(const u16* __restrict__ qkvp, u16* __restrict__ op) {
  const int blk = blockIdx.x;
  const int h = blk & 15, g = (blk >> 4) & 15, b = blk >> 8;
  const int tid = threadIdx.x, wave = tid >> 6, lane = tid & 63;
  const int lr = lane & 15, lg = lane >> 4;
  const int par = h & 1, hh = h >> 1;

  __shared__ u16 lQ[128 * 64];
  __shared__ u16 lK[128 * 64];
  __shared__ u16 lVt[64 * 128];
  __shared__ u16 lP[4][32 * 128];

  const u16* qp = qkvp + (size_t)par * (8192 * 1536);
  u16* opb = op + (size_t)par * (8192 * 512);
  const int rbase = (b << 11) + (g << 7);

#pragma unroll
  for (int i = 0; i < 4; ++i) {
    const int ou = i * 4096 + wave * 1024;
    const int o = ou + lane * 16;
    const int j = o >> 7, cb = o & 127;
    const u16* gq = qp + (size_t)(rbase + j) * 1536 + hh * 64 + (cb >> 1);
    GLDS16(gq, (char*)lQ + ou);
    GLDS16(gq + 512, (char*)lK + ou);
  }
#pragma unroll
  for (int i = 0; i < 4; ++i) {
    const int c = tid + i * 256;
    const int j = c >> 3, dc = c & 7;
    const uint4 vv = *(const uint4*)(qp + (size_t)(rbase + j) * 1536 + 1024 + hh * 64 + dc * 8);
    const u16* pv = (const u16*)&vv;
#pragma unroll
    for (int e = 0; e < 8; ++e) lVt[(dc * 8 + e) * 128 + j] = pv[e];
  }
  __syncthreads();

  f32x4 sacc[2][8] = {};
#pragma unroll
  for (int kk = 0; kk < 2; ++kk) {
    bf16x8 aq[2], bk[8];
#pragma unroll
    for (int mf = 0; mf < 2; ++mf)
      aq[mf] = *(const bf16x8*)&lQ[(wave * 32 + mf * 16 + lr) * 64 + kk * 32 + lg * 8];
#pragma unroll
    for (int nf = 0; nf < 8; ++nf)
      bk[nf] = *(const bf16x8*)&lK[(nf * 16 + lr) * 64 + kk * 32 + lg * 8];
#pragma unroll
    for (int mf = 0; mf < 2; ++mf)
#pragma unroll
      for (int nf = 0; nf < 8; ++nf)
        sacc[mf][nf] = __builtin_amdgcn_mfma_f32_16x16x32_bf16(aq[mf], bk[nf], sacc[mf][nf], 0, 0, 0);
  }

#pragma unroll
  for (int mf = 0; mf < 2; ++mf) {
#pragma unroll
    for (int r = 0; r < 4; ++r) {
      float mx = -3e38f;
#pragma unroll
      for (int nf = 0; nf < 8; ++nf) mx = fmaxf(mx, sacc[mf][nf][r]);
#pragma unroll
      for (int d = 1; d < 16; d <<= 1) mx = fmaxf(mx, __shfl_xor(mx, d));
      float pv[8];
      float sum = 0.f;
#pragma unroll
      for (int nf = 0; nf < 8; ++nf) {
        pv[nf] = __expf((sacc[mf][nf][r] - mx) * 0.125f);
        sum += pv[nf];
      }
#pragma unroll
      for (int d = 1; d < 16; d <<= 1) sum += __shfl_xor(sum, d);
      const float inv = 1.f / sum;
      const int rrow = mf * 16 + lg * 4 + r;
#pragma unroll
      for (int nf = 0; nf < 8; ++nf)
        lP[wave][rrow * 128 + nf * 16 + lr] = f2b(pv[nf] * inv);
    }
  }
  __syncthreads();

  f32x4 oacc[2][4] = {};
#pragma unroll
  for (int kk = 0; kk < 4; ++kk) {
    bf16x8 ap[2], bv[4];
#pragma unroll
    for (int mf = 0; mf < 2; ++mf)
      ap[mf] = *(const bf16x8*)&lP[wave][(mf * 16 + lr) * 128 + kk * 32 + lg * 8];
#pragma unroll
    for (int nf = 0; nf < 4; ++nf)
      bv[nf] = *(const bf16x8*)&lVt[(nf * 16 + lr) * 128 + kk * 32 + lg * 8];
#pragma unroll
    for (int mf = 0; mf < 2; ++mf)
#pragma unroll
      for (int nf = 0; nf < 4; ++nf)
        oacc[mf][nf] = __builtin_amdgcn_mfma_f32_16x16x32_bf16(ap[mf], bv[nf], oacc[mf][nf], 0, 0, 0);
  }

  u16* obase = opb + (size_t)rbase * 512 + hh * 64;
#pragma unroll
  for (int mf = 0; mf < 2; ++mf)
#pragma unroll
    for (int nf = 0; nf < 4; ++nf)
#pragma unroll
      for (int r = 0; r < 4; ++r) {
        const int jq = wave * 32 + mf * 16 + lg * 4 + r;
        obase[(size_t)jq * 512 + nf * 16 + lr] = f2b(oacc[mf][nf][r]);
      }
}

// ---------------- launch ----------------
extern "C" void kernel_launch(void* const* d_in, const int* in_sizes, int n_in,
                              void* d_out, int out_size, void* d_ws, size_t ws_size,
                              hipStream_t stream) {
  const float* x    = (const float*)d_in[0];
  const float* ln1g = (const float*)d_in[1];
  const float* ln1b = (const float*)d_in[2];
  const float* wqkv = (const float*)d_in[3];
  const float* bqkv = (const float*)d_in[4];
  const float* wo   = (const float*)d_in[5];
  const float* bo   = (const float*)d_in[6];
  const float* ln2g = (const float*)d_in[7];
  const float* ln2b = (const float*)d_in[8];
  const float* w1   = (const float*)d_in[9];
  const float* b1   = (const float*)d_in[10];
  const float* w2   = (const float*)d_in[11];
  const float* b2   = (const float*)d_in[12];
  const int*   perm = (const int*)d_in[13];
  float* out = (float*)d_out;
  char* ws = (char*)d_ws;

  u16*  r0    = (u16*)ws;                         // 32 MB: LN1 out (bf16) / LN2 out (fp8)
  u8*   r8    = (u8*)ws;
  u16*  qkvp  = (u16*)(ws + (32ull << 20));       // 48 MB: [2][8192][1536]
  u16*  op    = (u16*)(ws + (80ull << 20));       // 16 MB: [2][8192][512]
  u16*  a1    = (u16*)(ws + (32ull << 20));       // 128 MB bf16 (qkvp/op dead by then)
  u16*  x2    = (u16*)(ws + (160ull << 20));      // 32 MB (bf16 residual)
  u16*  wqkvP = (u16*)(ws + (224ull << 20));      // 6 MB
  u16*  woP   = (u16*)(ws + (230ull << 20));      // 2 MB
  u8*   w1T8  = (u8*)(ws + (232ull << 20));       // 4 MB fp8
  u16*  w2T   = (u16*)(ws + (240ull << 20));      // 8 MB bf16

  transpose_qkv_pack<<<dim3(96, 32), 256, 0, stream>>>(wqkv, wqkvP);
  transpose_wo_pack<<<dim3(32, 32), 256, 0, stream>>>(wo, woP);
  transpose_fp8<<<dim3(4096 / 32, 1024 / 32), 256, 0, stream>>>(w1, w1T8, 1024, 4096);
  transpose_bf16<<<dim3(1024 / 32, 4096 / 32), 256, 0, stream>>>(w2, w2T, 4096, 1024);

  ln_rows<0, 0><<<16384, 256, 0, stream>>>(x, ln1g, ln1b, perm, r0);      // LN1(x)[perm] bf16
  gemm256<0, 1><<<384, 512, 0, stream>>>(r0, wqkvP, bqkv, qkvp, nullptr, nullptr,
                                         8192, 1536, 1024, 2048,
                                         1024L, 1536L * 1024, 8192L * 1536);
  attn_kernel<<<1024, 256, 0, stream>>>(qkvp, op);
  gemm256<2, 1><<<256, 512, 0, stream>>>(op, woP, bo, x2, x, perm,
                                         8192, 1024, 512, 512,
                                         8192L * 512, 1024L * 512, 0);
  ln_rows<1, 1><<<16384, 256, 0, stream>>>(x2, ln2g, ln2b, nullptr, r8);  // LN2 -> fp8 (x4)
  gemm_f8<<<1024, 512, 0, stream>>>(r8, w1T8, b1, a1, 16384, 4096, 1024); // a1 = gelu (bf16)
  gemm256<3, 0><<<256, 512, 0, stream>>>(a1, w2T, b2, out, x2, nullptr,
                                         16384, 1024, 4096, 4096, 0, 0, 0);
}